// Round 11
// baseline (295.226 us; speedup 1.0000x reference)
//
#include <hip/hip_runtime.h>
#include <stdint.h>

#define N_TOK 16384
#define DDIM  1024
#define HDIM  4096
#define NEXP  8
#define BM    256
#define MAXMT 72
#define MAXNR 5

#define GRID_W 16384    // combine_w blocks (first: starts BW work immediately)
#define GRID_B 128      // combine_b blocks
#define GRID_R 4096     // router blocks (4 tokens each, no LDS)

typedef __attribute__((ext_vector_type(8)))  short short8;
typedef __attribute__((ext_vector_type(4)))  float f32x4;
typedef __attribute__((ext_vector_type(16))) float f32x16;

__device__ __forceinline__ unsigned short f2b(float f) {
    union { float f; unsigned int u; } x; x.f = f;
    unsigned int r = x.u + 0x7FFFu + ((x.u >> 16) & 1u);
    return (unsigned short)(r >> 16);
}

// K1: FUSED prep — combine_w / combine_b / router(+bf16 cast), one launch.
// No static LDS (router reads Wr via L1/L2) => full occupancy for all blocks.
__global__ __launch_bounds__(256)
void k_fused(const float* __restrict__ x, const float* __restrict__ Wr,
             const float* __restrict__ br, unsigned short* __restrict__ xb,
             int* __restrict__ eid,
             const float* __restrict__ Ws, const float* __restrict__ We,
             unsigned short* __restrict__ wc,
             const float* __restrict__ bs, const float* __restrict__ be,
             float* __restrict__ bc)
{
    const int bid = blockIdx.x;
    const int t = threadIdx.x;

    if (bid < GRID_W) {
        // ---- combine_w: wc = bf16(Ws + We[e]) ----
        const size_t i = ((size_t)bid * 256 + t) * 8;
        const size_t hd = i & (size_t)(HDIM * DDIM - 1);
        float4 a0 = *(const float4*)(We + i);
        float4 a1 = *(const float4*)(We + i + 4);
        float4 b0 = *(const float4*)(Ws + hd);
        float4 b1 = *(const float4*)(Ws + hd + 4);
        uint4 o;
        o.x = f2b(a0.x + b0.x) | ((unsigned)f2b(a0.y + b0.y) << 16);
        o.y = f2b(a0.z + b0.z) | ((unsigned)f2b(a0.w + b0.w) << 16);
        o.z = f2b(a1.x + b1.x) | ((unsigned)f2b(a1.y + b1.y) << 16);
        o.w = f2b(a1.z + b1.z) | ((unsigned)f2b(a1.w + b1.w) << 16);
        *(uint4*)(wc + i) = o;
    } else if (bid < GRID_W + GRID_B) {
        // ---- combine_b: bc = bs + be[e] ----
        const int i = (bid - GRID_W) * 256 + t;
        bc[i] = bs[i & (HDIM - 1)] + be[i];
    } else {
        // ---- router: fp64 accumulate => argmax matches numpy; + x->bf16 ----
        const int lane = t & 63;
        const int n = (bid - GRID_W - GRID_B) * 4 + (t >> 6);
        const float* xr = x + (size_t)n * DDIM;
        double acc[NEXP];
#pragma unroll
        for (int e = 0; e < NEXP; ++e) acc[e] = 0.0;
#pragma unroll
        for (int j = 0; j < 4; ++j) {
            const int d = j * 256 + lane * 4;
            float4 v = *(const float4*)(xr + d);
            unsigned long long pk =
                (unsigned long long)(f2b(v.x) | ((unsigned int)f2b(v.y) << 16)) |
                ((unsigned long long)(f2b(v.z) | ((unsigned int)f2b(v.w) << 16)) << 32);
            *(unsigned long long*)(xb + (size_t)n * DDIM + d) = pk;
#pragma unroll
            for (int e = 0; e < NEXP; ++e) {
                float4 w = *(const float4*)(Wr + e * DDIM + d);   // L1/L2 hit
                acc[e] += (double)v.x * (double)w.x;
                acc[e] += (double)v.y * (double)w.y;
                acc[e] += (double)v.z * (double)w.z;
                acc[e] += (double)v.w * (double)w.w;
            }
        }
#pragma unroll
        for (int e = 0; e < NEXP; ++e)
#pragma unroll
            for (int off = 32; off > 0; off >>= 1)
                acc[e] += __shfl_down(acc[e], off);
        if (lane == 0) {
            double best = acc[0] + (double)br[0];
            int bi = 0;
#pragma unroll
            for (int e = 1; e < NEXP; ++e) {
                double v = acc[e] + (double)br[e];
                if (v > best) { best = v; bi = e; }
            }
            eid[n] = bi;
        }
    }
}

// K2: histogram — LDS counts then <=8 padded (64B-stride) global atomics/block.
__global__ __launch_bounds__(256)
void k_hist(const int* __restrict__ eid, int* __restrict__ counts)
{
    __shared__ int h[NEXP];
    const int t = threadIdx.x;
    if (t < NEXP) h[t] = 0;
    __syncthreads();
    atomicAdd(&h[eid[blockIdx.x * 256 + t]], 1);
    __syncthreads();
    if (t < NEXP && h[t]) atomicAdd(&counts[t * 16], h[t]);
}

// K3: scatter — pbase derived inline from counts; LDS rank + one padded
// global atomic per (block, expert).
__global__ __launch_bounds__(256)
void k_scatter(const int* __restrict__ eid, const int* __restrict__ counts,
               int* __restrict__ cursors, int* __restrict__ perm)
{
    __shared__ int cl[NEXP];
    __shared__ int h[NEXP];
    __shared__ int base[NEXP];
    const int t = threadIdx.x;
    if (t < NEXP) { cl[t] = counts[t * 16]; h[t] = 0; }
    __syncthreads();
    const int n = blockIdx.x * 256 + t;
    const int e = eid[n];
    int p = 0;
#pragma unroll
    for (int ee = 0; ee < NEXP; ++ee)
        if (ee < e) p += (cl[ee] + 255) >> 8;
    const int pbase = p << 8;
    const int rank = atomicAdd(&h[e], 1);
    __syncthreads();
    if (t < NEXP) base[t] = h[t] ? atomicAdd(&cursors[t * 16], h[t]) : 0;
    __syncthreads();
    perm[pbase + base[e] + rank] = n;
}

// K4: PERSISTENT gathered GEMM — round-6 ring/schedule, MFMA switched to
// 32x32x16 bf16 (2495 vs 2176 TF ceiling, half the MFMA instructions).
// A/B frag: row=lane&31, k=(lane>>5)*8+j. C/D (verified m74/m101):
// col=lane&31, row=(reg&3)+8*(reg>>2)+4*(lane>>5).
#define SBAR()   __builtin_amdgcn_s_barrier()
#define SCHED0() __builtin_amdgcn_sched_barrier(0)
#define LGKM0()  asm volatile("s_waitcnt lgkmcnt(0)" ::: "memory")

__global__ __launch_bounds__(512, 2)
void k_gemm(const unsigned short* __restrict__ X, const unsigned short* __restrict__ W,
            const float* __restrict__ bc, const int* __restrict__ perm,
            const int* __restrict__ cnt, float* __restrict__ out)
{
    __shared__ unsigned short lds[65536];       // 128 KiB ring (2 buf x 4 halves)
    __shared__ int   toksLDS[MAXNR][256];
    __shared__ float biasLDS[MAXNR][256];

    const int base  = blockIdx.x;
    const int tnr   = base & 15;
    const int tmB   = base >> 4;

    int ntE[NEXP]; int realM = 0;
#pragma unroll
    for (int e = 0; e < NEXP; ++e) {
        ntE[e] = (cnt[e * 16] + 255) >> 8;
        realM += ntE[e];
    }
    const int nR = (realM - tmB + 15) >> 4;     // 4..5
    const int T  = nR << 4;

    const int t    = threadIdx.x;
    const int lane = t & 63;
    const int wid  = t >> 6;
    const int wm   = wid >> 2;                  // 0..1: rows wm*128
    const int wn   = wid & 3;                   // 0..3: cols wn*64

    const int srow    = t >> 3;                 // staging row 0..63
    const int schunkE = (((t & 7) ^ (srow & 7)) << 3);
    unsigned short* dstT = lds + (t << 3);

    // 32x32 fragment addressing
    const int rowL = lane & 31;
    const int row7 = rowL & 7;
    const int kla  = lane >> 5;                 // 0..1
    int kx[4];
#pragma unroll
    for (int ks = 0; ks < 4; ++ks) kx[ks] = (((ks << 1) + kla) ^ row7) << 3;
    const int aOff = ((2 + wm) << 13) + (rowL << 6);                 // shorts
    const int bOff = ((wn >> 1) << 13) + (((wn & 1) << 6) + rowL) << 6 > 0 ?
                     ((wn >> 1) << 13) + ((((wn & 1) << 6) + rowL) << 6) :
                     ((wn >> 1) << 13) + ((((wn & 1) << 6) + rowL) << 6);
    const int colBase = tnr * 256 + wn * 64 + rowL;

    int ePk = 0;
#pragma unroll
    for (int w = 0; w < MAXNR; ++w) {
        int ev = 0;
        if (w < nR) {
            const int tmW = tmB + (w << 4);
            int pre = 0;
#pragma unroll
            for (int e = 0; e < NEXP; ++e) {
                if (tmW >= pre) ev = e;
                pre += ntE[e];
            }
        }
        ePk |= (ev & 15) << (w << 2);
    }
    if (t < 256) {
#pragma unroll
        for (int w = 0; w < MAXNR; ++w) {
            if (w < nR) {
                toksLDS[w][t] = perm[(tmB + (w << 4)) * 256 + t];
                const int ev = (ePk >> (w << 2)) & 15;
                biasLDS[w][t] = bc[ev * HDIM + tnr * 256 + t];
            }
        }
    }
    __syncthreads();

    int tokCur[4], tokNext[4];
#pragma unroll
    for (int i = 0; i < 4; ++i) {
        int a = toksLDS[0][i * 64 + srow];
        tokCur[i] = a < 0 ? 0 : a;
        int b = (nR > 1) ? toksLDS[1][i * 64 + srow] : 0;
        tokNext[i] = b < 0 ? 0 : b;
    }

    f32x16 acc[4][2];
    {
        float b0 = biasLDS[0][wn * 64 + rowL];
        float b1 = biasLDS[0][wn * 64 + 32 + rowL];
#pragma unroll
        for (int m = 0; m < 4; ++m)
#pragma unroll
            for (int r = 0; r < 16; ++r) { acc[m][0][r] = b0; acc[m][1][r] = b1; }
    }
    short8 fa[4][4], fb[2][4];

    auto STAGE = [&](int sg, int tau) {
        if (sg >= (nR << 6)) return;
        const int tloc = sg >> 2;
        const int h    = sg & 3;
        const int kb   = (tloc & 15) << 6;
        unsigned short* d = dstT + ((tloc & 1) << 15) + (h << 13);
        const unsigned short *s0, *s1;
        if (h < 2) {
            const int wS = tloc >> 4;
            const int ee = (ePk >> (wS << 2)) & 15;
            const size_t r0 = (size_t)(ee * HDIM + tnr * 256 + h * 128 + srow) * DDIM
                              + schunkE + kb;
            s0 = W + r0; s1 = W + r0 + (size_t)64 * DDIM;
        } else {
            const bool nxt = (tloc >> 4) != (tau >> 4);
            const int i0 = (h - 2) << 1;
            const int ta = nxt ? tokNext[i0]     : tokCur[i0];
            const int tb = nxt ? tokNext[i0 + 1] : tokCur[i0 + 1];
            s0 = X + (size_t)ta * DDIM + schunkE + kb;
            s1 = X + (size_t)tb * DDIM + schunkE + kb;
        }
        __builtin_amdgcn_global_load_lds(
            (const __attribute__((address_space(1))) void*)s0,
            (__attribute__((address_space(3))) void*)d, 16, 0, 0);
        __builtin_amdgcn_global_load_lds(
            (const __attribute__((address_space(1))) void*)s1,
            (__attribute__((address_space(3))) void*)(d + 4096), 16, 0, 0);
    };

#define LDA(m,k) fa[m][k] = *(const short8*)&lds[bufOff + aOff + (m)*2048 + kx[k]];
#define LDB(n,k) fb[n][k] = *(const short8*)&lds[bufOff + bOff + (n)*2048 + kx[k]];
#define MM4(m,n) \
    acc[m][n] = __builtin_amdgcn_mfma_f32_32x32x16_bf16(fa[m][0], fb[n][0], acc[m][n], 0,0,0); \
    acc[m][n] = __builtin_amdgcn_mfma_f32_32x32x16_bf16(fa[m][1], fb[n][1], acc[m][n], 0,0,0); \
    acc[m][n] = __builtin_amdgcn_mfma_f32_32x32x16_bf16(fa[m][2], fb[n][2], acc[m][n], 0,0,0); \
    acc[m][n] = __builtin_amdgcn_mfma_f32_32x32x16_bf16(fa[m][3], fb[n][3], acc[m][n], 0,0,0);

    // ring prologue: tile0 fully landed; 3 half-tiles (6 loads) in flight
#pragma unroll
    for (int s = 0; s < 7; ++s) STAGE(s, 0);
    asm volatile("s_waitcnt vmcnt(6)" ::: "memory");
    SCHED0(); SBAR(); SCHED0();

    int w = 0;
#pragma unroll 1
    for (int tau = 0; tau < T; ++tau) {
        const int tt = tau & 15;
        const int bufOff = (tau & 1) << 15;
        const int sig = (tau << 2) + 7;

        // ---- tile top: 24 frag reads, FIFO groups [fb0,fb1,fa0] [fa1] [fa2,fa3]
        LDB(0,0) LDB(0,1) LDB(0,2) LDB(0,3)
        LDB(1,0) LDB(1,1) LDB(1,2) LDB(1,3)
        LDA(0,0) LDA(0,1) LDA(0,2) LDA(0,3)
        SCHED0();
        LDA(1,0) LDA(1,1) LDA(1,2) LDA(1,3)
        SCHED0();
        LDA(2,0) LDA(2,1) LDA(2,2) LDA(2,3)
        LDA(3,0) LDA(3,1) LDA(3,2) LDA(3,3)
        STAGE(sig, tau);                       // other-buffer H3: always safe
        SCHED0();
        asm volatile("s_waitcnt lgkmcnt(12)" ::: "memory"); SCHED0();
        __builtin_amdgcn_s_setprio(1);
        MM4(0,0) MM4(0,1)
        __builtin_amdgcn_s_setprio(0); SCHED0();
        asm volatile("s_waitcnt lgkmcnt(8)" ::: "memory"); SCHED0();
        __builtin_amdgcn_s_setprio(1);
        MM4(1,0) MM4(1,1)
        __builtin_amdgcn_s_setprio(0); SCHED0();
        // ---- mid barrier: all waves' reads complete -> safe to overwrite-stage
        LGKM0(); SBAR(); SCHED0();
        STAGE(sig + 1, tau); STAGE(sig + 2, tau); STAGE(sig + 3, tau);
        SCHED0();
        __builtin_amdgcn_s_setprio(1);
        MM4(2,0) MM4(2,1) MM4(3,0) MM4(3,1)
        __builtin_amdgcn_s_setprio(0); SCHED0();
        // ---- boundary: tile tau+1 fully landed, 3 stages in flight ----
        if (tau < T - 2)       { asm volatile("s_waitcnt vmcnt(6)" ::: "memory"); }
        else if (tau == T - 2) { asm volatile("s_waitcnt vmcnt(0)" ::: "memory"); }
        SBAR(); SCHED0();

        if (tt == 15) {
            // ---- epilogue for wg w: guarded scatter-store, C/D 32x32 layout
            const int rHi = (lane >> 5) << 2;   // 0 or 4
#pragma unroll
            for (int m = 0; m < 4; ++m) {
                int tk[16];
#pragma unroll
                for (int r = 0; r < 16; ++r) {
                    const int row = (r & 3) + ((r >> 2) << 3) + rHi + wm * 128 + m * 32;
                    tk[r] = toksLDS[w][row];
                }
#pragma unroll
                for (int n = 0; n < 2; ++n) {
                    const int col = colBase + n * 32;
#pragma unroll
                    for (int r = 0; r < 16; ++r)
                        if (tk[r] >= 0) out[(size_t)tk[r] * HDIM + col] = acc[m][n][r];
                }
            }
            if (w + 1 < nR) {
                const float b0 = biasLDS[w + 1][wn * 64 + rowL];
                const float b1 = biasLDS[w + 1][wn * 64 + 32 + rowL];
#pragma unroll
                for (int m = 0; m < 4; ++m)
#pragma unroll
                    for (int r = 0; r < 16; ++r) { acc[m][0][r] = b0; acc[m][1][r] = b1; }
#pragma unroll
                for (int i = 0; i < 4; ++i) tokCur[i] = tokNext[i];
                if (w + 2 < nR) {
#pragma unroll
                    for (int i = 0; i < 4; ++i) {
                        int v = toksLDS[w + 2][i * 64 + srow];
                        tokNext[i] = v < 0 ? 0 : v;
                    }
                }
            }
            ++w;
        }
    }
#undef LDA
#undef LDB
#undef MM4
}

extern "C" void kernel_launch(void* const* d_in, const int* in_sizes, int n_in,
                              void* d_out, int out_size, void* d_ws, size_t ws_size,
                              hipStream_t stream)
{
    const float* x  = (const float*)d_in[0];
    const float* Ws = (const float*)d_in[1];
    const float* bs = (const float*)d_in[2];
    const float* We = (const float*)d_in[3];
    const float* be = (const float*)d_in[4];
    const float* Wr = (const float*)d_in[5];
    const float* br = (const float*)d_in[6];
    float* out = (float*)d_out;
    char* ws = (char*)d_ws;

    unsigned short* xb  = (unsigned short*)(ws + 0);          // 33,554,432 B
    unsigned short* wc  = (unsigned short*)(ws + 33554432);   // 67,108,864 B
    float*          bc  = (float*)(ws + 100663296);           //    131,072 B
    int*            eid = (int*)(ws + 100794368);             //     65,536 B
    int*            perm= (int*)(ws + 100859904);             //     73,728 B
    int*            cnt = (int*)(ws + 100933632);             // 512 B (padded)
    int*            cur = (int*)(ws + 100934144);             // 512 B (padded)

    hipMemsetAsync(perm, 0xFF, MAXMT * BM * sizeof(int), stream);
    hipMemsetAsync(cnt, 0, 1024, stream);   // cnt + cur

    k_fused<<<GRID_W + GRID_B + GRID_R, 256, 0, stream>>>(
        x, Wr, br, xb, eid, Ws, We, wc, bs, be, bc);
    k_hist<<<N_TOK / 256, 256, 0, stream>>>(eid, cnt);
    k_scatter<<<N_TOK / 256, 256, 0, stream>>>(eid, cnt, cur, perm);
    k_gemm<<<256, 512, 0, stream>>>(xb, wc, bc, perm, cnt, out);
}

// Round 12
// 275.578 us; speedup vs baseline: 1.0713x; 1.0713x over previous
//
#include <hip/hip_runtime.h>
#include <stdint.h>

#define N_TOK 16384
#define DDIM  1024
#define HDIM  4096
#define NEXP  8
#define BM    256
#define MAXMT 72
#define MAXNR 5

#define GRID_W 16384    // combine_w blocks (first: starts BW work immediately)
#define GRID_B 128      // combine_b blocks
#define GRID_R 4096     // router blocks (4 tokens each, no big LDS)

typedef __attribute__((ext_vector_type(8))) short short8;
typedef __attribute__((ext_vector_type(4))) float f32x4;

__device__ __forceinline__ unsigned short f2b(float f) {
    union { float f; unsigned int u; } x; x.f = f;
    unsigned int r = x.u + 0x7FFFu + ((x.u >> 16) & 1u);
    return (unsigned short)(r >> 16);
}

// K1: FUSED prep — combine_w / combine_b / router(+bf16 cast +histogram).
// Router branch also accumulates the expert histogram (per-block LDS then
// <=8 padded global atomics) so the separate k_hist kernel is gone.
__global__ __launch_bounds__(256)
void k_fused(const float* __restrict__ x, const float* __restrict__ Wr,
             const float* __restrict__ br, unsigned short* __restrict__ xb,
             int* __restrict__ eid, int* __restrict__ counts,
             const float* __restrict__ Ws, const float* __restrict__ We,
             unsigned short* __restrict__ wc,
             const float* __restrict__ bs, const float* __restrict__ be,
             float* __restrict__ bc)
{
    __shared__ int h[NEXP];
    const int bid = blockIdx.x;
    const int t = threadIdx.x;

    if (bid < GRID_W) {
        // ---- combine_w: wc = bf16(Ws + We[e]) ----
        const size_t i = ((size_t)bid * 256 + t) * 8;
        const size_t hd = i & (size_t)(HDIM * DDIM - 1);
        float4 a0 = *(const float4*)(We + i);
        float4 a1 = *(const float4*)(We + i + 4);
        float4 b0 = *(const float4*)(Ws + hd);
        float4 b1 = *(const float4*)(Ws + hd + 4);
        uint4 o;
        o.x = f2b(a0.x + b0.x) | ((unsigned)f2b(a0.y + b0.y) << 16);
        o.y = f2b(a0.z + b0.z) | ((unsigned)f2b(a0.w + b0.w) << 16);
        o.z = f2b(a1.x + b1.x) | ((unsigned)f2b(a1.y + b1.y) << 16);
        o.w = f2b(a1.z + b1.z) | ((unsigned)f2b(a1.w + b1.w) << 16);
        *(uint4*)(wc + i) = o;
    } else if (bid < GRID_W + GRID_B) {
        // ---- combine_b: bc = bs + be[e] ----
        const int i = (bid - GRID_W) * 256 + t;
        bc[i] = bs[i & (HDIM - 1)] + be[i];
    } else {
        // ---- router: fp64 accumulate => argmax matches numpy; + x->bf16 ----
        if (t < NEXP) h[t] = 0;
        __syncthreads();
        const int lane = t & 63;
        const int n = (bid - GRID_W - GRID_B) * 4 + (t >> 6);
        const float* xr = x + (size_t)n * DDIM;
        double acc[NEXP];
#pragma unroll
        for (int e = 0; e < NEXP; ++e) acc[e] = 0.0;
#pragma unroll
        for (int j = 0; j < 4; ++j) {
            const int d = j * 256 + lane * 4;
            float4 v = *(const float4*)(xr + d);
            unsigned long long pk =
                (unsigned long long)(f2b(v.x) | ((unsigned int)f2b(v.y) << 16)) |
                ((unsigned long long)(f2b(v.z) | ((unsigned int)f2b(v.w) << 16)) << 32);
            *(unsigned long long*)(xb + (size_t)n * DDIM + d) = pk;
#pragma unroll
            for (int e = 0; e < NEXP; ++e) {
                float4 w = *(const float4*)(Wr + e * DDIM + d);   // L1/L2 hit
                acc[e] += (double)v.x * (double)w.x;
                acc[e] += (double)v.y * (double)w.y;
                acc[e] += (double)v.z * (double)w.z;
                acc[e] += (double)v.w * (double)w.w;
            }
        }
#pragma unroll
        for (int e = 0; e < NEXP; ++e)
#pragma unroll
            for (int off = 32; off > 0; off >>= 1)
                acc[e] += __shfl_down(acc[e], off);
        if (lane == 0) {
            double best = acc[0] + (double)br[0];
            int bi = 0;
#pragma unroll
            for (int e = 1; e < NEXP; ++e) {
                double v = acc[e] + (double)br[e];
                if (v > best) { best = v; bi = e; }
            }
            eid[n] = bi;
            atomicAdd(&h[bi], 1);             // LDS atomic
        }
        __syncthreads();
        if (t < NEXP && h[t]) atomicAdd(&counts[t * 16], h[t]);  // padded lines
    }
}

// K2: scatter — pbase derived inline from counts; LDS rank + one padded
// global atomic per (block, expert).
__global__ __launch_bounds__(256)
void k_scatter(const int* __restrict__ eid, const int* __restrict__ counts,
               int* __restrict__ cursors, int* __restrict__ perm)
{
    __shared__ int cl[NEXP];
    __shared__ int h[NEXP];
    __shared__ int base[NEXP];
    const int t = threadIdx.x;
    if (t < NEXP) { cl[t] = counts[t * 16]; h[t] = 0; }
    __syncthreads();
    const int n = blockIdx.x * 256 + t;
    const int e = eid[n];
    int p = 0;
#pragma unroll
    for (int ee = 0; ee < NEXP; ++ee)
        if (ee < e) p += (cl[ee] + 255) >> 8;
    const int pbase = p << 8;
    const int rank = atomicAdd(&h[e], 1);
    __syncthreads();
    if (t < NEXP) base[t] = h[t] ? atomicAdd(&cursors[t * 16], h[t]) : 0;
    __syncthreads();
    perm[pbase + base[e] + rank] = n;
}

// K3: PERSISTENT gathered GEMM — round-10 core verbatim (best measured:
// 188us). 16x16x32 bf16, 256x256 tile, BK=64, tile-top FIFO ds_reads gated
// by counted lgkmcnt, mid barrier + boundary counted vmcnt(6), T2 XOR
// swizzle (2-way alias = free), setprio on MFMA clusters.
#define SBAR()   __builtin_amdgcn_s_barrier()
#define SCHED0() __builtin_amdgcn_sched_barrier(0)
#define LGKM0()  asm volatile("s_waitcnt lgkmcnt(0)" ::: "memory")

__global__ __launch_bounds__(512, 2)
void k_gemm(const unsigned short* __restrict__ X, const unsigned short* __restrict__ W,
            const float* __restrict__ bc, const int* __restrict__ perm,
            const int* __restrict__ cnt, float* __restrict__ out)
{
    __shared__ unsigned short lds[65536];       // 128 KiB ring
    __shared__ int   toksLDS[MAXNR][256];
    __shared__ float biasLDS[MAXNR][256];

    const int base  = blockIdx.x;
    const int tnr   = base & 15;
    const int tmB   = base >> 4;

    int ntE[NEXP]; int realM = 0;
#pragma unroll
    for (int e = 0; e < NEXP; ++e) {
        ntE[e] = (cnt[e * 16] + 255) >> 8;
        realM += ntE[e];
    }
    const int nR = (realM - tmB + 15) >> 4;     // 4..5
    const int T  = nR << 4;

    const int t    = threadIdx.x;
    const int lane = t & 63;
    const int wid  = t >> 6;
    const int wm   = wid >> 2;
    const int wn   = wid & 3;

    const int srow    = t >> 3;                        // 0..63
    const int schunkE = (((t & 7) ^ (srow & 7)) << 3); // swizzled src k-offset
    unsigned short* dstT = lds + (t << 3);

    const int rA   = lane & 15;
    const int c0   = ((lane >> 4) << 3) ^ ((lane & 7) << 3);
    const int c1   = c0 ^ 32;
    const int aBase = ((2 + wm) << 13) + (rA << 6);
    const int bBase = ((wn >> 1) << 13) + ((wn & 1) << 12) + (rA << 6);
    const int colBase = tnr * 256 + wn * 64 + rA;

    int ePk = 0;
#pragma unroll
    for (int w = 0; w < MAXNR; ++w) {
        int ev = 0;
        if (w < nR) {
            const int tmW = tmB + (w << 4);
            int pre = 0;
#pragma unroll
            for (int e = 0; e < NEXP; ++e) {
                if (tmW >= pre) ev = e;
                pre += ntE[e];
            }
        }
        ePk |= (ev & 15) << (w << 2);
    }
    if (t < 256) {
#pragma unroll
        for (int w = 0; w < MAXNR; ++w) {
            if (w < nR) {
                toksLDS[w][t] = perm[(tmB + (w << 4)) * 256 + t];
                const int ev = (ePk >> (w << 2)) & 15;
                biasLDS[w][t] = bc[ev * HDIM + tnr * 256 + t];
            }
        }
    }
    __syncthreads();

    int tokCur[4], tokNext[4];
#pragma unroll
    for (int i = 0; i < 4; ++i) {
        int a = toksLDS[0][i * 64 + srow];
        tokCur[i] = a < 0 ? 0 : a;
        int b = (nR > 1) ? toksLDS[1][i * 64 + srow] : 0;
        tokNext[i] = b < 0 ? 0 : b;
    }

    f32x4 acc[8][4];
    {
        float bn[4];
#pragma unroll
        for (int n = 0; n < 4; ++n) bn[n] = biasLDS[0][wn * 64 + n * 16 + rA];
#pragma unroll
        for (int m = 0; m < 8; ++m)
#pragma unroll
            for (int n = 0; n < 4; ++n)
                acc[m][n] = (f32x4){bn[n], bn[n], bn[n], bn[n]};
    }
    short8 fa[8][2], fb[4][2];

    auto STAGE = [&](int sg, int tau) {
        if (sg >= (nR << 6)) return;
        const int tloc = sg >> 2;
        const int h    = sg & 3;
        const int kb   = (tloc & 15) << 6;
        unsigned short* d = dstT + ((tloc & 1) << 15) + (h << 13);
        const unsigned short *s0, *s1;
        if (h < 2) {
            const int wS = tloc >> 4;
            const int ee = (ePk >> (wS << 2)) & 15;
            const size_t r0 = (size_t)(ee * HDIM + tnr * 256 + h * 128 + srow) * DDIM
                              + schunkE + kb;
            s0 = W + r0; s1 = W + r0 + (size_t)64 * DDIM;
        } else {
            const bool nxt = (tloc >> 4) != (tau >> 4);
            const int i0 = (h - 2) << 1;
            const int ta = nxt ? tokNext[i0]     : tokCur[i0];
            const int tb = nxt ? tokNext[i0 + 1] : tokCur[i0 + 1];
            s0 = X + (size_t)ta * DDIM + schunkE + kb;
            s1 = X + (size_t)tb * DDIM + schunkE + kb;
        }
        __builtin_amdgcn_global_load_lds(
            (const __attribute__((address_space(1))) void*)s0,
            (__attribute__((address_space(3))) void*)d, 16, 0, 0);
        __builtin_amdgcn_global_load_lds(
            (const __attribute__((address_space(1))) void*)s1,
            (__attribute__((address_space(3))) void*)(d + 4096), 16, 0, 0);
    };

#define LDA(m) \
    fa[m][0] = *(const short8*)&lds[bufOff + aBase + (m)*1024 + c0]; \
    fa[m][1] = *(const short8*)&lds[bufOff + aBase + (m)*1024 + c1];
#define LDB(n) \
    fb[n][0] = *(const short8*)&lds[bufOff + bBase + (n)*1024 + c0]; \
    fb[n][1] = *(const short8*)&lds[bufOff + bBase + (n)*1024 + c1];
#define MM(m,n) \
    acc[m][n] = __builtin_amdgcn_mfma_f32_16x16x32_bf16(fa[m][0], fb[n][0], acc[m][n], 0,0,0); \
    acc[m][n] = __builtin_amdgcn_mfma_f32_16x16x32_bf16(fa[m][1], fb[n][1], acc[m][n], 0,0,0);

    // ring prologue: tile0 fully landed; 3 half-tiles (6 loads) stay in flight
#pragma unroll
    for (int s = 0; s < 7; ++s) STAGE(s, 0);
    asm volatile("s_waitcnt vmcnt(6)" ::: "memory");
    SCHED0(); SBAR(); SCHED0();

    int w = 0;
#pragma unroll 1
    for (int tau = 0; tau < T; ++tau) {
        const int tt = tau & 15;
        const int bufOff = (tau & 1) << 15;
        const int sig = (tau << 2) + 7;

        // ---- tile top: all fragment reads, FIFO-grouped ----
        LDB(0) LDB(1) LDB(2) LDB(3) LDA(0) LDA(1)    // G1: 12 reads
        SCHED0();
        LDA(2) LDA(3)                                // G2: 4 reads
        SCHED0();
        LDA(4) LDA(5) LDA(6) LDA(7)                  // G3: 8 reads
        STAGE(sig, tau);                             // other-buffer H3: always safe
        SCHED0();
        asm volatile("s_waitcnt lgkmcnt(12)" ::: "memory"); SCHED0();
        __builtin_amdgcn_s_setprio(1);
        MM(0,0) MM(0,1) MM(0,2) MM(0,3) MM(1,0) MM(1,1) MM(1,2) MM(1,3)
        __builtin_amdgcn_s_setprio(0); SCHED0();
        asm volatile("s_waitcnt lgkmcnt(8)" ::: "memory"); SCHED0();
        __builtin_amdgcn_s_setprio(1);
        MM(2,0) MM(2,1) MM(2,2) MM(2,3) MM(3,0) MM(3,1) MM(3,2) MM(3,3)
        __builtin_amdgcn_s_setprio(0); SCHED0();
        // ---- mid barrier: all waves' reads complete -> safe to overwrite-stage
        LGKM0(); SBAR(); SCHED0();
        STAGE(sig + 1, tau); STAGE(sig + 2, tau); STAGE(sig + 3, tau);
        SCHED0();
        __builtin_amdgcn_s_setprio(1);
        MM(4,0) MM(4,1) MM(4,2) MM(4,3) MM(5,0) MM(5,1) MM(5,2) MM(5,3)
        MM(6,0) MM(6,1) MM(6,2) MM(6,3) MM(7,0) MM(7,1) MM(7,2) MM(7,3)
        __builtin_amdgcn_s_setprio(0); SCHED0();
        // ---- boundary: tile tau+1 fully landed, 3 stages in flight ----
        if (tau < T - 2)       { asm volatile("s_waitcnt vmcnt(6)" ::: "memory"); }
        else if (tau == T - 2) { asm volatile("s_waitcnt vmcnt(0)" ::: "memory"); }
        SBAR(); SCHED0();

        if (tt == 15) {
            // ---- epilogue for wg w: pure guarded scatter-store ----
            const int rsub = (lane >> 4) * 4;
#pragma unroll
            for (int m = 0; m < 8; ++m) {
                const int rl = wm * 128 + m * 16 + rsub;
                int tk[4];
#pragma unroll
                for (int j = 0; j < 4; ++j) tk[j] = toksLDS[w][rl + j];
#pragma unroll
                for (int n = 0; n < 4; ++n) {
                    const int col = colBase + n * 16;
#pragma unroll
                    for (int j = 0; j < 4; ++j)
                        if (tk[j] >= 0) out[(size_t)tk[j] * HDIM + col] = acc[m][n][j];
                }
            }
            if (w + 1 < nR) {
                float bn[4];
#pragma unroll
                for (int n = 0; n < 4; ++n) bn[n] = biasLDS[w + 1][wn * 64 + n * 16 + rA];
#pragma unroll
                for (int m = 0; m < 8; ++m)
#pragma unroll
                    for (int n = 0; n < 4; ++n)
                        acc[m][n] = (f32x4){bn[n], bn[n], bn[n], bn[n]};
#pragma unroll
                for (int i = 0; i < 4; ++i) tokCur[i] = tokNext[i];
                if (w + 2 < nR) {
#pragma unroll
                    for (int i = 0; i < 4; ++i) {
                        int v = toksLDS[w + 2][i * 64 + srow];
                        tokNext[i] = v < 0 ? 0 : v;
                    }
                }
            }
            ++w;
        }
    }
#undef LDA
#undef LDB
#undef MM
}

extern "C" void kernel_launch(void* const* d_in, const int* in_sizes, int n_in,
                              void* d_out, int out_size, void* d_ws, size_t ws_size,
                              hipStream_t stream)
{
    const float* x  = (const float*)d_in[0];
    const float* Ws = (const float*)d_in[1];
    const float* bs = (const float*)d_in[2];
    const float* We = (const float*)d_in[3];
    const float* be = (const float*)d_in[4];
    const float* Wr = (const float*)d_in[5];
    const float* br = (const float*)d_in[6];
    float* out = (float*)d_out;
    char* ws = (char*)d_ws;

    unsigned short* xb  = (unsigned short*)(ws + 0);          // 33,554,432 B
    unsigned short* wc  = (unsigned short*)(ws + 33554432);   // 67,108,864 B
    float*          bc  = (float*)(ws + 100663296);           //    131,072 B
    int*            eid = (int*)(ws + 100794368);             //     65,536 B
    int*            perm= (int*)(ws + 100859904);             //     73,728 B
    int*            cnt = (int*)(ws + 100933632);             // 512 B (padded)
    int*            cur = (int*)(ws + 100934144);             // 512 B (padded)

    hipMemsetAsync(perm, 0xFF, MAXMT * BM * sizeof(int), stream);
    hipMemsetAsync(cnt, 0, 1024, stream);   // cnt + cur

    k_fused<<<GRID_W + GRID_B + GRID_R, 256, 0, stream>>>(
        x, Wr, br, xb, eid, cnt, Ws, We, wc, bs, be, bc);
    k_scatter<<<N_TOK / 256, 256, 0, stream>>>(eid, cnt, cur, perm);
    k_gemm<<<256, 512, 0, stream>>>(xb, wc, bc, perm, cnt, out);
}

// Round 14
// 271.476 us; speedup vs baseline: 1.0875x; 1.0151x over previous
//
#include <hip/hip_runtime.h>
#include <stdint.h>

#define N_TOK 16384
#define DDIM  1024
#define HDIM  4096
#define NEXP  8
#define BM    256
#define MAXMT 72
#define MAXNR 5

#define GRID_R 4096     // router blocks (4 tokens each)
#define GRID_W 16384    // combine_w blocks
#define GRID_B 128      // combine_b blocks

typedef __attribute__((ext_vector_type(8))) short short8;
typedef __attribute__((ext_vector_type(4))) float f32x4;

__device__ __forceinline__ unsigned short f2b(float f) {
    union { float f; unsigned int u; } x; x.f = f;
    unsigned int r = x.u + 0x7FFFu + ((x.u >> 16) & 1u);
    return (unsigned short)(r >> 16);
}

// K1: FUSED prep — three independent jobs in one launch (stream would
// otherwise serialize them): router(+bf16 cast) / combine_w / combine_b.
__global__ __launch_bounds__(256)
void k_fused(const float* __restrict__ x, const float* __restrict__ Wr,
             const float* __restrict__ br, unsigned short* __restrict__ xb,
             int* __restrict__ eid,
             const float* __restrict__ Ws, const float* __restrict__ We,
             unsigned short* __restrict__ wc,
             const float* __restrict__ bs, const float* __restrict__ be,
             float* __restrict__ bc)
{
    const int bid = blockIdx.x;
    const int t = threadIdx.x;

    if (bid < GRID_R) {
        // ---- router: fp64 accumulate => argmax matches numpy; + x->bf16 ----
        __shared__ float wr[NEXP * DDIM];
        for (int i = t; i < NEXP * DDIM / 4; i += 256)
            ((float4*)wr)[i] = ((const float4*)Wr)[i];
        __syncthreads();
        const int lane = t & 63;
        const int n = bid * 4 + (t >> 6);
        const float* xr = x + (size_t)n * DDIM;
        double acc[NEXP];
#pragma unroll
        for (int e = 0; e < NEXP; ++e) acc[e] = 0.0;
#pragma unroll
        for (int j = 0; j < 4; ++j) {
            const int d = j * 256 + lane * 4;
            float4 v = *(const float4*)(xr + d);
            unsigned long long pk =
                (unsigned long long)(f2b(v.x) | ((unsigned int)f2b(v.y) << 16)) |
                ((unsigned long long)(f2b(v.z) | ((unsigned int)f2b(v.w) << 16)) << 32);
            *(unsigned long long*)(xb + (size_t)n * DDIM + d) = pk;
#pragma unroll
            for (int e = 0; e < NEXP; ++e) {
                const float* w = wr + e * DDIM + d;
                acc[e] += (double)v.x * (double)w[0];
                acc[e] += (double)v.y * (double)w[1];
                acc[e] += (double)v.z * (double)w[2];
                acc[e] += (double)v.w * (double)w[3];
            }
        }
#pragma unroll
        for (int e = 0; e < NEXP; ++e)
#pragma unroll
            for (int off = 32; off > 0; off >>= 1)
                acc[e] += __shfl_down(acc[e], off);
        if (lane == 0) {
            double best = acc[0] + (double)br[0];
            int bi = 0;
#pragma unroll
            for (int e = 1; e < NEXP; ++e) {
                double v = acc[e] + (double)br[e];
                if (v > best) { best = v; bi = e; }
            }
            eid[n] = bi;
        }
    } else if (bid < GRID_R + GRID_W) {
        // ---- combine_w: wc = bf16(Ws + We[e]) ----
        const size_t i = ((size_t)(bid - GRID_R) * 256 + t) * 8;
        const size_t hd = i & (size_t)(HDIM * DDIM - 1);
        float4 a0 = *(const float4*)(We + i);
        float4 a1 = *(const float4*)(We + i + 4);
        float4 b0 = *(const float4*)(Ws + hd);
        float4 b1 = *(const float4*)(Ws + hd + 4);
        uint4 o;
        o.x = f2b(a0.x + b0.x) | ((unsigned)f2b(a0.y + b0.y) << 16);
        o.y = f2b(a0.z + b0.z) | ((unsigned)f2b(a0.w + b0.w) << 16);
        o.z = f2b(a1.x + b1.x) | ((unsigned)f2b(a1.y + b1.y) << 16);
        o.w = f2b(a1.z + b1.z) | ((unsigned)f2b(a1.w + b1.w) << 16);
        *(uint4*)(wc + i) = o;
    } else {
        // ---- combine_b: bc = bs + be[e] ----
        const int i = (bid - GRID_R - GRID_W) * 256 + t;
        bc[i] = bs[i & (HDIM - 1)] + be[i];
    }
}

// K2: histogram — LDS counts then <=8 padded (64B-stride) global atomics/block.
__global__ __launch_bounds__(256)
void k_hist(const int* __restrict__ eid, int* __restrict__ counts)
{
    __shared__ int h[NEXP];
    const int t = threadIdx.x;
    if (t < NEXP) h[t] = 0;
    __syncthreads();
    atomicAdd(&h[eid[blockIdx.x * 256 + t]], 1);
    __syncthreads();
    if (t < NEXP && h[t]) atomicAdd(&counts[t * 16], h[t]);
}

// K3: scatter — pbase derived inline from counts; LDS rank + one padded
// global atomic per (block, expert).
__global__ __launch_bounds__(256)
void k_scatter(const int* __restrict__ eid, const int* __restrict__ counts,
               int* __restrict__ cursors, int* __restrict__ perm)
{
    __shared__ int cl[NEXP];
    __shared__ int h[NEXP];
    __shared__ int base[NEXP];
    const int t = threadIdx.x;
    if (t < NEXP) { cl[t] = counts[t * 16]; h[t] = 0; }
    __syncthreads();
    const int n = blockIdx.x * 256 + t;
    const int e = eid[n];
    int p = 0;
#pragma unroll
    for (int ee = 0; ee < NEXP; ++ee)
        if (ee < e) p += (cl[ee] + 255) >> 8;
    const int pbase = p << 8;
    const int rank = atomicAdd(&h[e], 1);
    __syncthreads();
    if (t < NEXP) base[t] = h[t] ? atomicAdd(&cursors[t * 16], h[t]) : 0;
    __syncthreads();
    perm[pbase + base[e] + rank] = n;
}

// K4: PERSISTENT gathered GEMM — best measured core (188us). 16x16x32 bf16,
// 256x256 tile, BK=64, tile-top FIFO ds_reads gated by counted lgkmcnt,
// mid barrier + boundary counted vmcnt(6), T2 XOR swizzle, setprio.
#define SBAR()   __builtin_amdgcn_s_barrier()
#define SCHED0() __builtin_amdgcn_sched_barrier(0)
#define LGKM0()  asm volatile("s_waitcnt lgkmcnt(0)" ::: "memory")

__global__ __launch_bounds__(512, 2)
void k_gemm(const unsigned short* __restrict__ X, const unsigned short* __restrict__ W,
            const float* __restrict__ bc, const int* __restrict__ perm,
            const int* __restrict__ cnt, float* __restrict__ out)
{
    __shared__ unsigned short lds[65536];       // 128 KiB ring
    __shared__ int   toksLDS[MAXNR][256];
    __shared__ float biasLDS[MAXNR][256];

    const int base  = blockIdx.x;
    const int tnr   = base & 15;
    const int tmB   = base >> 4;

    int ntE[NEXP]; int realM = 0;
#pragma unroll
    for (int e = 0; e < NEXP; ++e) {
        ntE[e] = (cnt[e * 16] + 255) >> 8;
        realM += ntE[e];
    }
    const int nR = (realM - tmB + 15) >> 4;     // 4..5
    const int T  = nR << 4;

    const int t    = threadIdx.x;
    const int lane = t & 63;
    const int wid  = t >> 6;
    const int wm   = wid >> 2;
    const int wn   = wid & 3;

    const int srow    = t >> 3;                        // 0..63
    const int schunkE = (((t & 7) ^ (srow & 7)) << 3); // swizzled src k-offset
    unsigned short* dstT = lds + (t << 3);

    const int rA   = lane & 15;
    const int c0   = ((lane >> 4) << 3) ^ ((lane & 7) << 3);
    const int c1   = c0 ^ 32;
    const int aBase = ((2 + wm) << 13) + (rA << 6);
    const int bBase = ((wn >> 1) << 13) + ((wn & 1) << 12) + (rA << 6);
    const int colBase = tnr * 256 + wn * 64 + rA;

    int ePk = 0;
#pragma unroll
    for (int w = 0; w < MAXNR; ++w) {
        int ev = 0;
        if (w < nR) {
            const int tmW = tmB + (w << 4);
            int pre = 0;
#pragma unroll
            for (int e = 0; e < NEXP; ++e) {
                if (tmW >= pre) ev = e;
                pre += ntE[e];
            }
        }
        ePk |= (ev & 15) << (w << 2);
    }
    if (t < 256) {
#pragma unroll
        for (int w = 0; w < MAXNR; ++w) {
            if (w < nR) {
                toksLDS[w][t] = perm[(tmB + (w << 4)) * 256 + t];
                const int ev = (ePk >> (w << 2)) & 15;
                biasLDS[w][t] = bc[ev * HDIM + tnr * 256 + t];
            }
        }
    }
    __syncthreads();

    int tokCur[4], tokNext[4];
#pragma unroll
    for (int i = 0; i < 4; ++i) {
        int a = toksLDS[0][i * 64 + srow];
        tokCur[i] = a < 0 ? 0 : a;
        int b = (nR > 1) ? toksLDS[1][i * 64 + srow] : 0;
        tokNext[i] = b < 0 ? 0 : b;
    }

    f32x4 acc[8][4];
    {
        float bn[4];
#pragma unroll
        for (int n = 0; n < 4; ++n) bn[n] = biasLDS[0][wn * 64 + n * 16 + rA];
#pragma unroll
        for (int m = 0; m < 8; ++m)
#pragma unroll
            for (int n = 0; n < 4; ++n)
                acc[m][n] = (f32x4){bn[n], bn[n], bn[n], bn[n]};
    }
    short8 fa[8][2], fb[4][2];

    auto STAGE = [&](int sg, int tau) {
        if (sg >= (nR << 6)) return;
        const int tloc = sg >> 2;
        const int h    = sg & 3;
        const int kb   = (tloc & 15) << 6;
        unsigned short* d = dstT + ((tloc & 1) << 15) + (h << 13);
        const unsigned short *s0, *s1;
        if (h < 2) {
            const int wS = tloc >> 4;
            const int ee = (ePk >> (wS << 2)) & 15;
            const size_t r0 = (size_t)(ee * HDIM + tnr * 256 + h * 128 + srow) * DDIM
                              + schunkE + kb;
            s0 = W + r0; s1 = W + r0 + (size_t)64 * DDIM;
        } else {
            const bool nxt = (tloc >> 4) != (tau >> 4);
            const int i0 = (h - 2) << 1;
            const int ta = nxt ? tokNext[i0]     : tokCur[i0];
            const int tb = nxt ? tokNext[i0 + 1] : tokCur[i0 + 1];
            s0 = X + (size_t)ta * DDIM + schunkE + kb;
            s1 = X + (size_t)tb * DDIM + schunkE + kb;
        }
        __builtin_amdgcn_global_load_lds(
            (const __attribute__((address_space(1))) void*)s0,
            (__attribute__((address_space(3))) void*)d, 16, 0, 0);
        __builtin_amdgcn_global_load_lds(
            (const __attribute__((address_space(1))) void*)s1,
            (__attribute__((address_space(3))) void*)(d + 4096), 16, 0, 0);
    };

#define LDA(m) \
    fa[m][0] = *(const short8*)&lds[bufOff + aBase + (m)*1024 + c0]; \
    fa[m][1] = *(const short8*)&lds[bufOff + aBase + (m)*1024 + c1];
#define LDB(n) \
    fb[n][0] = *(const short8*)&lds[bufOff + bBase + (n)*1024 + c0]; \
    fb[n][1] = *(const short8*)&lds[bufOff + bBase + (n)*1024 + c1];
#define MM(m,n) \
    acc[m][n] = __builtin_amdgcn_mfma_f32_16x16x32_bf16(fa[m][0], fb[n][0], acc[m][n], 0,0,0); \
    acc[m][n] = __builtin_amdgcn_mfma_f32_16x16x32_bf16(fa[m][1], fb[n][1], acc[m][n], 0,0,0);

    // ring prologue: tile0 fully landed; 3 half-tiles (6 loads) stay in flight
#pragma unroll
    for (int s = 0; s < 7; ++s) STAGE(s, 0);
    asm volatile("s_waitcnt vmcnt(6)" ::: "memory");
    SCHED0(); SBAR(); SCHED0();

    int w = 0;
#pragma unroll 1
    for (int tau = 0; tau < T; ++tau) {
        const int tt = tau & 15;
        const int bufOff = (tau & 1) << 15;
        const int sig = (tau << 2) + 7;

        // ---- tile top: all fragment reads, FIFO-grouped ----
        LDB(0) LDB(1) LDB(2) LDB(3) LDA(0) LDA(1)    // G1: 12 reads
        SCHED0();
        LDA(2) LDA(3)                                // G2: 4 reads
        SCHED0();
        LDA(4) LDA(5) LDA(6) LDA(7)                  // G3: 8 reads
        STAGE(sig, tau);                             // other-buffer H3: always safe
        SCHED0();
        asm volatile("s_waitcnt lgkmcnt(12)" ::: "memory"); SCHED0();
        __builtin_amdgcn_s_setprio(1);
        MM(0,0) MM(0,1) MM(0,2) MM(0,3) MM(1,0) MM(1,1) MM(1,2) MM(1,3)
        __builtin_amdgcn_s_setprio(0); SCHED0();
        asm volatile("s_waitcnt lgkmcnt(8)" ::: "memory"); SCHED0();
        __builtin_amdgcn_s_setprio(1);
        MM(2,0) MM(2,1) MM(2,2) MM(2,3) MM(3,0) MM(3,1) MM(3,2) MM(3,3)
        __builtin_amdgcn_s_setprio(0); SCHED0();
        // ---- mid barrier: all waves' reads complete -> safe to overwrite-stage
        LGKM0(); SBAR(); SCHED0();
        STAGE(sig + 1, tau); STAGE(sig + 2, tau); STAGE(sig + 3, tau);
        SCHED0();
        __builtin_amdgcn_s_setprio(1);
        MM(4,0) MM(4,1) MM(4,2) MM(4,3) MM(5,0) MM(5,1) MM(5,2) MM(5,3)
        MM(6,0) MM(6,1) MM(6,2) MM(6,3) MM(7,0) MM(7,1) MM(7,2) MM(7,3)
        __builtin_amdgcn_s_setprio(0); SCHED0();
        // ---- boundary: tile tau+1 fully landed, 3 stages in flight ----
        if (tau < T - 2)       { asm volatile("s_waitcnt vmcnt(6)" ::: "memory"); }
        else if (tau == T - 2) { asm volatile("s_waitcnt vmcnt(0)" ::: "memory"); }
        SBAR(); SCHED0();

        if (tt == 15) {
            // ---- epilogue for wg w: pure guarded scatter-store ----
            const int rsub = (lane >> 4) * 4;
#pragma unroll
            for (int m = 0; m < 8; ++m) {
                const int rl = wm * 128 + m * 16 + rsub;
                int tk[4];
#pragma unroll
                for (int j = 0; j < 4; ++j) tk[j] = toksLDS[w][rl + j];
#pragma unroll
                for (int n = 0; n < 4; ++n) {
                    const int col = colBase + n * 16;
#pragma unroll
                    for (int j = 0; j < 4; ++j)
                        if (tk[j] >= 0) out[(size_t)tk[j] * HDIM + col] = acc[m][n][j];
                }
            }
            if (w + 1 < nR) {
                float bn[4];
#pragma unroll
                for (int n = 0; n < 4; ++n) bn[n] = biasLDS[w + 1][wn * 64 + n * 16 + rA];
#pragma unroll
                for (int m = 0; m < 8; ++m)
#pragma unroll
                    for (int n = 0; n < 4; ++n)
                        acc[m][n] = (f32x4){bn[n], bn[n], bn[n], bn[n]};
#pragma unroll
                for (int i = 0; i < 4; ++i) tokCur[i] = tokNext[i];
                if (w + 2 < nR) {
#pragma unroll
                    for (int i = 0; i < 4; ++i) {
                        int v = toksLDS[w + 2][i * 64 + srow];
                        tokNext[i] = v < 0 ? 0 : v;
                    }
                }
            }
            ++w;
        }
    }
#undef LDA
#undef LDB
#undef MM
}

extern "C" void kernel_launch(void* const* d_in, const int* in_sizes, int n_in,
                              void* d_out, int out_size, void* d_ws, size_t ws_size,
                              hipStream_t stream)
{
    const float* x  = (const float*)d_in[0];
    const float* Ws = (const float*)d_in[1];
    const float* bs = (const float*)d_in[2];
    const float* We = (const float*)d_in[3];
    const float* be = (const float*)d_in[4];
    const float* Wr = (const float*)d_in[5];
    const float* br = (const float*)d_in[6];
    float* out = (float*)d_out;
    char* ws = (char*)d_ws;

    unsigned short* xb  = (unsigned short*)(ws + 0);          // 33,554,432 B
    unsigned short* wc  = (unsigned short*)(ws + 33554432);   // 67,108,864 B
    float*          bc  = (float*)(ws + 100663296);           //    131,072 B
    int*            eid = (int*)(ws + 100794368);             //     65,536 B
    int*            perm= (int*)(ws + 100859904);             //     73,728 B
    int*            cnt = (int*)(ws + 100933632);             // 512 B (padded)
    int*            cur = (int*)(ws + 100934144);             // 512 B (padded)

    hipMemsetAsync(perm, 0xFF, MAXMT * BM * sizeof(int), stream);
    hipMemsetAsync(cnt, 0, 1024, stream);   // cnt + cur

    k_fused<<<GRID_R + GRID_W + GRID_B, 256, 0, stream>>>(
        x, Wr, br, xb, eid, Ws, We, wc, bs, be, bc);
    k_hist<<<N_TOK / 256, 256, 0, stream>>>(eid, cnt);
    k_scatter<<<N_TOK / 256, 256, 0, stream>>>(eid, cnt, cur, perm);
    k_gemm<<<256, 512, 0, stream>>>(xb, wc, bc, perm, cnt, out);
}

// Round 15
// 264.241 us; speedup vs baseline: 1.1173x; 1.0274x over previous
//
#include <hip/hip_runtime.h>
#include <stdint.h>

#define N_TOK 16384
#define DDIM  1024
#define HDIM  4096
#define NEXP  8
#define BM    256
#define MAXMT 72
#define MAXNR 5

#define GRID_R 4096     // router blocks (4 tokens each)
#define GRID_W 16384    // combine_w blocks
#define GRID_B 128      // combine_b blocks (also clear perm/cnt/cur)

#define NCLR_PERM 18432 // perm ints (MAXMT*BM)
#define NCLR_ALL  18688 // perm + cnt(64) + cur(64) + pad -> 18432+256

typedef __attribute__((ext_vector_type(8))) short short8;
typedef __attribute__((ext_vector_type(4))) float f32x4;

__device__ __forceinline__ unsigned short f2b(float f) {
    union { float f; unsigned int u; } x; x.f = f;
    unsigned int r = x.u + 0x7FFFu + ((x.u >> 16) & 1u);
    return (unsigned short)(r >> 16);
}

// K1: FUSED prep — router(+bf16 cast) / combine_w / combine_b(+metadata clear).
// The combine_b blocks also initialize perm=-1 and cnt/cur=0 (contiguous
// 18688 ints), replacing two hipMemsetAsync dispatches. Stream ordering
// guarantees completion before k_hist/k_scatter/k_gemm.
__global__ __launch_bounds__(256)
void k_fused(const float* __restrict__ x, const float* __restrict__ Wr,
             const float* __restrict__ br, unsigned short* __restrict__ xb,
             int* __restrict__ eid,
             const float* __restrict__ Ws, const float* __restrict__ We,
             unsigned short* __restrict__ wc,
             const float* __restrict__ bs, const float* __restrict__ be,
             float* __restrict__ bc, int* __restrict__ clr)
{
    const int bid = blockIdx.x;
    const int t = threadIdx.x;

    if (bid < GRID_R) {
        // ---- router: fp64 accumulate => argmax matches numpy; + x->bf16 ----
        __shared__ float wr[NEXP * DDIM];
        for (int i = t; i < NEXP * DDIM / 4; i += 256)
            ((float4*)wr)[i] = ((const float4*)Wr)[i];
        __syncthreads();
        const int lane = t & 63;
        const int n = bid * 4 + (t >> 6);
        const float* xr = x + (size_t)n * DDIM;
        double acc[NEXP];
#pragma unroll
        for (int e = 0; e < NEXP; ++e) acc[e] = 0.0;
#pragma unroll
        for (int j = 0; j < 4; ++j) {
            const int d = j * 256 + lane * 4;
            float4 v = *(const float4*)(xr + d);
            unsigned long long pk =
                (unsigned long long)(f2b(v.x) | ((unsigned int)f2b(v.y) << 16)) |
                ((unsigned long long)(f2b(v.z) | ((unsigned int)f2b(v.w) << 16)) << 32);
            *(unsigned long long*)(xb + (size_t)n * DDIM + d) = pk;
#pragma unroll
            for (int e = 0; e < NEXP; ++e) {
                const float* w = wr + e * DDIM + d;
                acc[e] += (double)v.x * (double)w[0];
                acc[e] += (double)v.y * (double)w[1];
                acc[e] += (double)v.z * (double)w[2];
                acc[e] += (double)v.w * (double)w[3];
            }
        }
#pragma unroll
        for (int e = 0; e < NEXP; ++e)
#pragma unroll
            for (int off = 32; off > 0; off >>= 1)
                acc[e] += __shfl_down(acc[e], off);
        if (lane == 0) {
            double best = acc[0] + (double)br[0];
            int bi = 0;
#pragma unroll
            for (int e = 1; e < NEXP; ++e) {
                double v = acc[e] + (double)br[e];
                if (v > best) { best = v; bi = e; }
            }
            eid[n] = bi;
        }
    } else if (bid < GRID_R + GRID_W) {
        // ---- combine_w: wc = bf16(Ws + We[e]) ----
        const size_t i = ((size_t)(bid - GRID_R) * 256 + t) * 8;
        const size_t hd = i & (size_t)(HDIM * DDIM - 1);
        float4 a0 = *(const float4*)(We + i);
        float4 a1 = *(const float4*)(We + i + 4);
        float4 b0 = *(const float4*)(Ws + hd);
        float4 b1 = *(const float4*)(Ws + hd + 4);
        uint4 o;
        o.x = f2b(a0.x + b0.x) | ((unsigned)f2b(a0.y + b0.y) << 16);
        o.y = f2b(a0.z + b0.z) | ((unsigned)f2b(a0.w + b0.w) << 16);
        o.z = f2b(a1.x + b1.x) | ((unsigned)f2b(a1.y + b1.y) << 16);
        o.w = f2b(a1.z + b1.z) | ((unsigned)f2b(a1.w + b1.w) << 16);
        *(uint4*)(wc + i) = o;
    } else {
        // ---- combine_b: bc = bs + be[e]; + metadata clear ----
        const int bl = bid - GRID_R - GRID_W;
        const int i = bl * 256 + t;
        bc[i] = bs[i & (HDIM - 1)] + be[i];
        if (i < NCLR_ALL) clr[i] = (i < NCLR_PERM) ? -1 : 0;
    }
}

// K2: histogram — LDS counts then <=8 padded (64B-stride) global atomics/block.
__global__ __launch_bounds__(256)
void k_hist(const int* __restrict__ eid, int* __restrict__ counts)
{
    __shared__ int h[NEXP];
    const int t = threadIdx.x;
    if (t < NEXP) h[t] = 0;
    __syncthreads();
    atomicAdd(&h[eid[blockIdx.x * 256 + t]], 1);
    __syncthreads();
    if (t < NEXP && h[t]) atomicAdd(&counts[t * 16], h[t]);
}

// K3: scatter — pbase derived inline from counts; LDS rank + one padded
// global atomic per (block, expert).
__global__ __launch_bounds__(256)
void k_scatter(const int* __restrict__ eid, const int* __restrict__ counts,
               int* __restrict__ cursors, int* __restrict__ perm)
{
    __shared__ int cl[NEXP];
    __shared__ int h[NEXP];
    __shared__ int base[NEXP];
    const int t = threadIdx.x;
    if (t < NEXP) { cl[t] = counts[t * 16]; h[t] = 0; }
    __syncthreads();
    const int n = blockIdx.x * 256 + t;
    const int e = eid[n];
    int p = 0;
#pragma unroll
    for (int ee = 0; ee < NEXP; ++ee)
        if (ee < e) p += (cl[ee] + 255) >> 8;
    const int pbase = p << 8;
    const int rank = atomicAdd(&h[e], 1);
    __syncthreads();
    if (t < NEXP) base[t] = h[t] ? atomicAdd(&cursors[t * 16], h[t]) : 0;
    __syncthreads();
    perm[pbase + base[e] + rank] = n;
}

// K4: PERSISTENT gathered GEMM — best measured core (186-190us). 16x16x32
// bf16, 256x256 tile, BK=64, tile-top FIFO ds_reads gated by counted
// lgkmcnt, mid barrier + boundary counted vmcnt(6), T2 XOR swizzle, setprio.
#define SBAR()   __builtin_amdgcn_s_barrier()
#define SCHED0() __builtin_amdgcn_sched_barrier(0)
#define LGKM0()  asm volatile("s_waitcnt lgkmcnt(0)" ::: "memory")

__global__ __launch_bounds__(512, 2)
void k_gemm(const unsigned short* __restrict__ X, const unsigned short* __restrict__ W,
            const float* __restrict__ bc, const int* __restrict__ perm,
            const int* __restrict__ cnt, float* __restrict__ out)
{
    __shared__ unsigned short lds[65536];       // 128 KiB ring
    __shared__ int   toksLDS[MAXNR][256];
    __shared__ float biasLDS[MAXNR][256];

    const int base  = blockIdx.x;
    const int tnr   = base & 15;
    const int tmB   = base >> 4;

    int ntE[NEXP]; int realM = 0;
#pragma unroll
    for (int e = 0; e < NEXP; ++e) {
        ntE[e] = (cnt[e * 16] + 255) >> 8;
        realM += ntE[e];
    }
    const int nR = (realM - tmB + 15) >> 4;     // 4..5
    const int T  = nR << 4;

    const int t    = threadIdx.x;
    const int lane = t & 63;
    const int wid  = t >> 6;
    const int wm   = wid >> 2;
    const int wn   = wid & 3;

    const int srow    = t >> 3;                        // 0..63
    const int schunkE = (((t & 7) ^ (srow & 7)) << 3); // swizzled src k-offset
    unsigned short* dstT = lds + (t << 3);

    const int rA   = lane & 15;
    const int c0   = ((lane >> 4) << 3) ^ ((lane & 7) << 3);
    const int c1   = c0 ^ 32;
    const int aBase = ((2 + wm) << 13) + (rA << 6);
    const int bBase = ((wn >> 1) << 13) + ((wn & 1) << 12) + (rA << 6);
    const int colBase = tnr * 256 + wn * 64 + rA;

    int ePk = 0;
#pragma unroll
    for (int w = 0; w < MAXNR; ++w) {
        int ev = 0;
        if (w < nR) {
            const int tmW = tmB + (w << 4);
            int pre = 0;
#pragma unroll
            for (int e = 0; e < NEXP; ++e) {
                if (tmW >= pre) ev = e;
                pre += ntE[e];
            }
        }
        ePk |= (ev & 15) << (w << 2);
    }
    if (t < 256) {
#pragma unroll
        for (int w = 0; w < MAXNR; ++w) {
            if (w < nR) {
                toksLDS[w][t] = perm[(tmB + (w << 4)) * 256 + t];
                const int ev = (ePk >> (w << 2)) & 15;
                biasLDS[w][t] = bc[ev * HDIM + tnr * 256 + t];
            }
        }
    }
    __syncthreads();

    int tokCur[4], tokNext[4];
#pragma unroll
    for (int i = 0; i < 4; ++i) {
        int a = toksLDS[0][i * 64 + srow];
        tokCur[i] = a < 0 ? 0 : a;
        int b = (nR > 1) ? toksLDS[1][i * 64 + srow] : 0;
        tokNext[i] = b < 0 ? 0 : b;
    }

    f32x4 acc[8][4];
    {
        float bn[4];
#pragma unroll
        for (int n = 0; n < 4; ++n) bn[n] = biasLDS[0][wn * 64 + n * 16 + rA];
#pragma unroll
        for (int m = 0; m < 8; ++m)
#pragma unroll
            for (int n = 0; n < 4; ++n)
                acc[m][n] = (f32x4){bn[n], bn[n], bn[n], bn[n]};
    }
    short8 fa[8][2], fb[4][2];

    auto STAGE = [&](int sg, int tau) {
        if (sg >= (nR << 6)) return;
        const int tloc = sg >> 2;
        const int h    = sg & 3;
        const int kb   = (tloc & 15) << 6;
        unsigned short* d = dstT + ((tloc & 1) << 15) + (h << 13);
        const unsigned short *s0, *s1;
        if (h < 2) {
            const int wS = tloc >> 4;
            const int ee = (ePk >> (wS << 2)) & 15;
            const size_t r0 = (size_t)(ee * HDIM + tnr * 256 + h * 128 + srow) * DDIM
                              + schunkE + kb;
            s0 = W + r0; s1 = W + r0 + (size_t)64 * DDIM;
        } else {
            const bool nxt = (tloc >> 4) != (tau >> 4);
            const int i0 = (h - 2) << 1;
            const int ta = nxt ? tokNext[i0]     : tokCur[i0];
            const int tb = nxt ? tokNext[i0 + 1] : tokCur[i0 + 1];
            s0 = X + (size_t)ta * DDIM + schunkE + kb;
            s1 = X + (size_t)tb * DDIM + schunkE + kb;
        }
        __builtin_amdgcn_global_load_lds(
            (const __attribute__((address_space(1))) void*)s0,
            (__attribute__((address_space(3))) void*)d, 16, 0, 0);
        __builtin_amdgcn_global_load_lds(
            (const __attribute__((address_space(1))) void*)s1,
            (__attribute__((address_space(3))) void*)(d + 4096), 16, 0, 0);
    };

#define LDA(m) \
    fa[m][0] = *(const short8*)&lds[bufOff + aBase + (m)*1024 + c0]; \
    fa[m][1] = *(const short8*)&lds[bufOff + aBase + (m)*1024 + c1];
#define LDB(n) \
    fb[n][0] = *(const short8*)&lds[bufOff + bBase + (n)*1024 + c0]; \
    fb[n][1] = *(const short8*)&lds[bufOff + bBase + (n)*1024 + c1];
#define MM(m,n) \
    acc[m][n] = __builtin_amdgcn_mfma_f32_16x16x32_bf16(fa[m][0], fb[n][0], acc[m][n], 0,0,0); \
    acc[m][n] = __builtin_amdgcn_mfma_f32_16x16x32_bf16(fa[m][1], fb[n][1], acc[m][n], 0,0,0);

    // ring prologue: tile0 fully landed; 3 half-tiles (6 loads) stay in flight
#pragma unroll
    for (int s = 0; s < 7; ++s) STAGE(s, 0);
    asm volatile("s_waitcnt vmcnt(6)" ::: "memory");
    SCHED0(); SBAR(); SCHED0();

    int w = 0;
#pragma unroll 1
    for (int tau = 0; tau < T; ++tau) {
        const int tt = tau & 15;
        const int bufOff = (tau & 1) << 15;
        const int sig = (tau << 2) + 7;

        // ---- tile top: all fragment reads, FIFO-grouped ----
        LDB(0) LDB(1) LDB(2) LDB(3) LDA(0) LDA(1)    // G1: 12 reads
        SCHED0();
        LDA(2) LDA(3)                                // G2: 4 reads
        SCHED0();
        LDA(4) LDA(5) LDA(6) LDA(7)                  // G3: 8 reads
        STAGE(sig, tau);                             // other-buffer H3: always safe
        SCHED0();
        asm volatile("s_waitcnt lgkmcnt(12)" ::: "memory"); SCHED0();
        __builtin_amdgcn_s_setprio(1);
        MM(0,0) MM(0,1) MM(0,2) MM(0,3) MM(1,0) MM(1,1) MM(1,2) MM(1,3)
        __builtin_amdgcn_s_setprio(0); SCHED0();
        asm volatile("s_waitcnt lgkmcnt(8)" ::: "memory"); SCHED0();
        __builtin_amdgcn_s_setprio(1);
        MM(2,0) MM(2,1) MM(2,2) MM(2,3) MM(3,0) MM(3,1) MM(3,2) MM(3,3)
        __builtin_amdgcn_s_setprio(0); SCHED0();
        // ---- mid barrier: all waves' reads complete -> safe to overwrite-stage
        LGKM0(); SBAR(); SCHED0();
        STAGE(sig + 1, tau); STAGE(sig + 2, tau); STAGE(sig + 3, tau);
        SCHED0();
        __builtin_amdgcn_s_setprio(1);
        MM(4,0) MM(4,1) MM(4,2) MM(4,3) MM(5,0) MM(5,1) MM(5,2) MM(5,3)
        MM(6,0) MM(6,1) MM(6,2) MM(6,3) MM(7,0) MM(7,1) MM(7,2) MM(7,3)
        __builtin_amdgcn_s_setprio(0); SCHED0();
        // ---- boundary: tile tau+1 fully landed, 3 stages in flight ----
        if (tau < T - 2)       { asm volatile("s_waitcnt vmcnt(6)" ::: "memory"); }
        else if (tau == T - 2) { asm volatile("s_waitcnt vmcnt(0)" ::: "memory"); }
        SBAR(); SCHED0();

        if (tt == 15) {
            // ---- epilogue for wg w: pure guarded scatter-store ----
            const int rsub = (lane >> 4) * 4;
#pragma unroll
            for (int m = 0; m < 8; ++m) {
                const int rl = wm * 128 + m * 16 + rsub;
                int tk[4];
#pragma unroll
                for (int j = 0; j < 4; ++j) tk[j] = toksLDS[w][rl + j];
#pragma unroll
                for (int n = 0; n < 4; ++n) {
                    const int col = colBase + n * 16;
#pragma unroll
                    for (int j = 0; j < 4; ++j)
                        if (tk[j] >= 0) out[(size_t)tk[j] * HDIM + col] = acc[m][n][j];
                }
            }
            if (w + 1 < nR) {
                float bn[4];
#pragma unroll
                for (int n = 0; n < 4; ++n) bn[n] = biasLDS[w + 1][wn * 64 + n * 16 + rA];
#pragma unroll
                for (int m = 0; m < 8; ++m)
#pragma unroll
                    for (int n = 0; n < 4; ++n)
                        acc[m][n] = (f32x4){bn[n], bn[n], bn[n], bn[n]};
#pragma unroll
                for (int i = 0; i < 4; ++i) tokCur[i] = tokNext[i];
                if (w + 2 < nR) {
#pragma unroll
                    for (int i = 0; i < 4; ++i) {
                        int v = toksLDS[w + 2][i * 64 + srow];
                        tokNext[i] = v < 0 ? 0 : v;
                    }
                }
            }
            ++w;
        }
    }
#undef LDA
#undef LDB
#undef MM
}

extern "C" void kernel_launch(void* const* d_in, const int* in_sizes, int n_in,
                              void* d_out, int out_size, void* d_ws, size_t ws_size,
                              hipStream_t stream)
{
    const float* x  = (const float*)d_in[0];
    const float* Ws = (const float*)d_in[1];
    const float* bs = (const float*)d_in[2];
    const float* We = (const float*)d_in[3];
    const float* be = (const float*)d_in[4];
    const float* Wr = (const float*)d_in[5];
    const float* br = (const float*)d_in[6];
    float* out = (float*)d_out;
    char* ws = (char*)d_ws;

    unsigned short* xb  = (unsigned short*)(ws + 0);          // 33,554,432 B
    unsigned short* wc  = (unsigned short*)(ws + 33554432);   // 67,108,864 B
    float*          bc  = (float*)(ws + 100663296);           //    131,072 B
    int*            eid = (int*)(ws + 100794368);             //     65,536 B
    int*            perm= (int*)(ws + 100859904);             //     73,728 B
    int*            cnt = (int*)(ws + 100933632);             // 512 B (padded)
    int*            cur = (int*)(ws + 100934144);             // 512 B (padded)
    // perm..cur are contiguous: cleared by k_fused combine_b blocks (18688 ints)

    k_fused<<<GRID_R + GRID_W + GRID_B, 256, 0, stream>>>(
        x, Wr, br, xb, eid, Ws, We, wc, bs, be, bc, perm);
    k_hist<<<N_TOK / 256, 256, 0, stream>>>(eid, cnt);
    k_scatter<<<N_TOK / 256, 256, 0, stream>>>(eid, cnt, cur, perm);
    k_gemm<<<256, 512, 0, stream>>>(xb, wc, bc, perm, cnt, out);
}